// Round 1
// baseline (530.121 us; speedup 1.0000x reference)
//
#include <hip/hip_runtime.h>
#include <math.h>

#define N_IMG 8192
#define GROUPS 16
#define EMB 1600   // 5*5*64

// ---------------------------------------------------------------------------
// Fused per-image pipeline: conv1(3x3,1->32)+ReLU+pool2 -> conv2(3x3,32->64)
// +ReLU+pool2 -> 1600-d embedding -> atomicAdd into per-group (img>>9) sums.
// One workgroup (320 threads = 5 waves) per image.
// LDS: image 784 f32 + pooled1 [32][13][16] (row stride 16 for aligned float4)
// Conv2 only computed at rows/cols 0..9 (row/col 10 dropped by VALID pool).
// ---------------------------------------------------------------------------
__global__ __launch_bounds__(320) void fused_conv(
        const float* __restrict__ x,
        const float* __restrict__ w1, const float* __restrict__ b1,
        const float* __restrict__ w2, const float* __restrict__ b2,
        float* __restrict__ gsum)
{
    __shared__ float simg[28 * 28];
    __shared__ __align__(16) float sp1[32 * 13 * 16];  // [ci][row][col(16)]

    const int img = blockIdx.x;
    const int tid = threadIdx.x;

    // ---- stage 0: image -> LDS (coalesced) ----
    {
        const float* xi = x + img * 784;
        for (int i = tid; i < 784; i += 320) simg[i] = xi[i];
    }
    __syncthreads();

    // ---- stage 1: conv1 + relu + maxpool2 -> sp1[ci][r][c] ----
    {
        const int co    = tid & 31;   // output channel 0..31
        const int slice = tid >> 5;   // 0..9 position slice
        float w[9];
        #pragma unroll
        for (int t = 0; t < 9; ++t) w[t] = w1[t * 32 + co];
        const float bias = b1[co];

        for (int p = slice; p < 169; p += 10) {
            const int r = p / 13, c = p % 13;
            // 4x4 input patch at (2r, 2c)
            float in[4][4];
            #pragma unroll
            for (int i = 0; i < 4; ++i)
                #pragma unroll
                for (int j = 0; j < 4; ++j)
                    in[i][j] = simg[(2 * r + i) * 28 + (2 * c + j)];
            float m = 0.f;  // relu floor
            #pragma unroll
            for (int dy = 0; dy < 2; ++dy)
                #pragma unroll
                for (int dx = 0; dx < 2; ++dx) {
                    float v = bias;
                    #pragma unroll
                    for (int ky = 0; ky < 3; ++ky)
                        #pragma unroll
                        for (int kx = 0; kx < 3; ++kx)
                            v = fmaf(in[dy + ky][dx + kx], w[ky * 3 + kx], v);
                    m = fmaxf(m, v);
                }
            sp1[co * 208 + r * 16 + c] = m;
        }
    }
    __syncthreads();

    // ---- stage 2: conv2 + relu + maxpool2 -> embedding, atomic group add ----
    {
        const int ch = tid & 63;   // output channel 0..63
        const int pr = tid >> 6;   // pooled row 0..4
        const int y0 = 2 * pr;     // conv rows y0, y0+1

        float acc0[10], acc1[10];
        const float bias = b2[ch];
        #pragma unroll
        for (int i = 0; i < 10; ++i) { acc0[i] = bias; acc1[i] = bias; }

        for (int ci = 0; ci < 32; ++ci) {
            float w[9];
            #pragma unroll
            for (int t = 0; t < 9; ++t) w[t] = w2[(t * 32 + ci) * 64 + ch];
            const float* base = &sp1[ci * 208];
            #pragma unroll
            for (int r4 = 0; r4 < 4; ++r4) {
                const int row = y0 + r4;
                // 12 cols as 3 aligned float4 (wave-uniform -> LDS broadcast)
                const float4* rp = (const float4*)(base + row * 16);
                const float4 A = rp[0], B = rp[1], C = rp[2];
                const float rin[12] = {A.x, A.y, A.z, A.w,
                                       B.x, B.y, B.z, B.w,
                                       C.x, C.y, C.z, C.w};
                if (r4 < 3) {  // contributes to conv row y0 with ky=r4
                    const float wk0 = w[r4 * 3], wk1 = w[r4 * 3 + 1], wk2 = w[r4 * 3 + 2];
                    #pragma unroll
                    for (int xx = 0; xx < 10; ++xx)
                        acc0[xx] = fmaf(rin[xx], wk0,
                                   fmaf(rin[xx + 1], wk1,
                                   fmaf(rin[xx + 2], wk2, acc0[xx])));
                }
                if (r4 >= 1) {  // contributes to conv row y0+1 with ky=r4-1
                    const float wk0 = w[(r4 - 1) * 3], wk1 = w[(r4 - 1) * 3 + 1], wk2 = w[(r4 - 1) * 3 + 2];
                    #pragma unroll
                    for (int xx = 0; xx < 10; ++xx)
                        acc1[xx] = fmaf(rin[xx], wk0,
                                   fmaf(rin[xx + 1], wk1,
                                   fmaf(rin[xx + 2], wk2, acc1[xx])));
                }
            }
        }

        // relu + pool + accumulate into group sum
        float* gs = gsum + (img >> 9) * EMB;
        #pragma unroll
        for (int pc = 0; pc < 5; ++pc) {
            float m = fmaxf(fmaxf(acc0[2 * pc], acc0[2 * pc + 1]),
                            fmaxf(acc1[2 * pc], acc1[2 * pc + 1]));
            m = fmaxf(m, 0.f);
            atomicAdd(&gs[(pr * 5 + pc) * 64 + ch], m);
        }
    }
}

// ---------------------------------------------------------------------------
// Head: mean (/512) -> max over 16 groups -> fc1 (linear) -> fc2 -> sigmoid
// ---------------------------------------------------------------------------
__global__ __launch_bounds__(512) void head(
        const float* __restrict__ gsum,
        const float* __restrict__ fc1w, const float* __restrict__ fc1b,
        const float* __restrict__ fc2w, const float* __restrict__ fc2b,
        float* __restrict__ out)
{
    __shared__ float souter[EMB];
    __shared__ float sred[512];
    const int tid = threadIdx.x;

    for (int d = tid; d < EMB; d += 512) {
        float m = -INFINITY;
        #pragma unroll
        for (int g = 0; g < GROUPS; ++g) m = fmaxf(m, gsum[g * EMB + d]);
        souter[d] = m * (1.f / 512.f);
    }
    __syncthreads();

    float pj = fc1b[tid];
    for (int d = 0; d < EMB; ++d)
        pj = fmaf(souter[d], fc1w[d * 512 + tid], pj);

    sred[tid] = pj * fc2w[tid];
    __syncthreads();
    for (int s = 256; s > 0; s >>= 1) {
        if (tid < s) sred[tid] += sred[tid + s];
        __syncthreads();
    }
    if (tid == 0) {
        const float z = sred[0] + fc2b[0];
        out[0] = 1.f / (1.f + expf(-z));
    }
}

extern "C" void kernel_launch(void* const* d_in, const int* in_sizes, int n_in,
                              void* d_out, int out_size, void* d_ws, size_t ws_size,
                              hipStream_t stream)
{
    const float* x    = (const float*)d_in[0];
    const float* w1   = (const float*)d_in[1];
    const float* b1   = (const float*)d_in[2];
    const float* w2   = (const float*)d_in[3];
    const float* b2   = (const float*)d_in[4];
    const float* fc1w = (const float*)d_in[5];
    const float* fc1b = (const float*)d_in[6];
    const float* fc2w = (const float*)d_in[7];
    const float* fc2b = (const float*)d_in[8];
    // d_in[9] first_lab, d_in[10] second_lab: contiguous equal-size bags
    // (i//32 then //16) == mean over 512 consecutive images, group = img>>9.

    float* gsum = (float*)d_ws;  // [16][1600] f32 group sums
    hipMemsetAsync(gsum, 0, GROUPS * EMB * sizeof(float), stream);

    fused_conv<<<N_IMG, 320, 0, stream>>>(x, w1, b1, w2, b2, gsum);
    head<<<1, 512, 0, stream>>>(gsum, fc1w, fc1b, fc2w, fc2b, (float*)d_out);
}

// Round 2
// 141.142 us; speedup vs baseline: 3.7560x; 3.7560x over previous
//
#include <hip/hip_runtime.h>
#include <math.h>

#define N_IMG 8192
#define GROUPS 16
#define EMB 1600
#define IPB 4            // images per block

typedef __attribute__((ext_vector_type(8))) short short8;
typedef __attribute__((ext_vector_type(4))) float f32x4;

// ws layout (bytes): gsum [16*1600 f32] @0 ; w2f [18432 bf16] @102400 ; v [1600 f32] @139264
#define WS_W2F 102400
#define WS_V   139264

__device__ __forceinline__ unsigned short f2bf(float f) {
    unsigned u = __builtin_bit_cast(unsigned, f);
    u = (u + 0x7FFFu + ((u >> 16) & 1u)) >> 16;   // RNE
    return (unsigned short)u;
}

// Pack w2 (f32 [3][3][32][64]) -> bf16 frag order w2f[s][g][n][j] ;
// flat i = s*2048 + g*512 + n*8 + j  where k = ci = 8g+j, s = ky*3+kx.
__global__ void prep_w2(const float* __restrict__ w2, unsigned short* __restrict__ w2f) {
    int i = blockIdx.x * 256 + threadIdx.x;
    if (i < 18432) {
        int j = i & 7, n = (i >> 3) & 63, g = (i >> 9) & 3, s = i >> 11;
        w2f[i] = f2bf(w2[(s * 32 + 8 * g + j) * 64 + n]);
    }
}

// v[d] = sum_j fc1w[d][j] * fc2w[j]   (fc1 and fc2 are linear -> collapse)
__global__ void prep_v(const float* __restrict__ fc1w, const float* __restrict__ fc2w,
                       float* __restrict__ v) {
    int d = blockIdx.x * 64 + threadIdx.x;
    if (d >= EMB) return;
    const float4* a = (const float4*)(fc1w + d * 512);
    const float4* b = (const float4*)fc2w;
    float s = 0.f;
    for (int q = 0; q < 128; ++q) {
        float4 av = a[q], bv = b[q];
        s += av.x * bv.x + av.y * bv.y + av.z * bv.z + av.w * bv.w;
    }
    v[d] = s;
}

// ---------------------------------------------------------------------------
// Fused: per block: 4 images. conv1(fp32)->LDS bf16 frags -> conv2 via MFMA
// -> sconv(LDS f32) -> pool/relu -> register accum -> 1 atomic per addr/block
// ---------------------------------------------------------------------------
__global__ __launch_bounds__(256) void fused(
        const float* __restrict__ x,
        const float* __restrict__ w1, const float* __restrict__ b1,
        const unsigned short* __restrict__ w2f, const float* __restrict__ b2,
        float* __restrict__ gsum)
{
    __shared__ float simg[784];
    __shared__ __align__(16) unsigned short sp2[4 * 169 * 8]; // [g][cell13x13][8ch] bf16
    __shared__ float sconv[100 * 66];                          // [pos10x10][ch(66 pad)]

    const int tid = threadIdx.x;
    const int w  = tid >> 6;          // wave 0..3
    const int mw = w & 1, nw = w >> 1;
    const int g  = (tid >> 4) & 3;    // k-group
    const int l15 = tid & 15;

    // B fragments: bb[s][jn], jn = n-tile (channels 32nw+16jn .. +15)
    short8 bb[9][2];
    #pragma unroll
    for (int s = 0; s < 9; ++s)
        #pragma unroll
        for (int j = 0; j < 2; ++j) {
            int n = 32 * nw + 16 * j + l15;
            bb[s][j] = *(const short8*)(w2f + ((s * 4 + g) * 64 + n) * 8);
        }
    const float bias0 = b2[32 * nw + l15];
    const float bias1 = b2[32 * nw + 16 + l15];

    // pool accumulators: thread handles channel pch, positions pbase+4i
    const int pch = tid & 63, pbase = tid >> 6;
    float pacc[7] = {0.f, 0.f, 0.f, 0.f, 0.f, 0.f, 0.f};

    for (int ii = 0; ii < IPB; ++ii) {
        const int img = blockIdx.x * IPB + ii;
        __syncthreads();
        { // image -> LDS
            const float* xi = x + img * 784;
            for (int i = tid; i < 784; i += 256) simg[i] = xi[i];
        }
        __syncthreads();
        { // conv1 + relu + pool (only the 12x12 cells conv2 needs)
            const int co = tid & 31, sl = tid >> 5;
            float wv[9];
            #pragma unroll
            for (int t = 0; t < 9; ++t) wv[t] = w1[t * 32 + co];
            const float b = b1[co];
            for (int p = sl; p < 144; p += 8) {
                const int r = p / 12, c = p - r * 12;
                float in[4][4];
                #pragma unroll
                for (int i = 0; i < 4; ++i)
                    #pragma unroll
                    for (int j = 0; j < 4; ++j)
                        in[i][j] = simg[(2 * r + i) * 28 + (2 * c + j)];
                float m = 0.f;
                #pragma unroll
                for (int dy = 0; dy < 2; ++dy)
                    #pragma unroll
                    for (int dx = 0; dx < 2; ++dx) {
                        float vv = b;
                        #pragma unroll
                        for (int ky = 0; ky < 3; ++ky)
                            #pragma unroll
                            for (int kx = 0; kx < 3; ++kx)
                                vv = fmaf(in[dy + ky][dx + kx], wv[ky * 3 + kx], vv);
                        m = fmaxf(m, vv);
                    }
                sp2[((co >> 3) * 169 + r * 13 + c) * 8 + (co & 7)] = f2bf(m);
            }
        }
        __syncthreads();
        { // conv2 via MFMA: wave (mw,nw): M-tiles t=mw,mw+2,.., N = 32nw..32nw+31
            for (int t = mw; t < 7; t += 2) {
                int p = 16 * t + l15; if (p > 99) p = 99;
                const int r = p / 10, c = p - r * 10;
                const unsigned short* abase = sp2 + (g * 169 + r * 13 + c) * 8;
                f32x4 a0 = {bias0, bias0, bias0, bias0};
                f32x4 a1 = {bias1, bias1, bias1, bias1};
                #pragma unroll
                for (int s = 0; s < 9; ++s) {
                    short8 af = *(const short8*)(abase + ((s / 3) * 13 + (s % 3)) * 8);
                    a0 = __builtin_amdgcn_mfma_f32_16x16x32_bf16(af, bb[s][0], a0, 0, 0, 0);
                    a1 = __builtin_amdgcn_mfma_f32_16x16x32_bf16(af, bb[s][1], a1, 0, 0, 0);
                }
                #pragma unroll
                for (int reg = 0; reg < 4; ++reg) {
                    const int row = 16 * t + 4 * g + reg;
                    if (row < 100) {
                        sconv[row * 66 + 32 * nw + l15]      = a0[reg];
                        sconv[row * 66 + 32 * nw + 16 + l15] = a1[reg];
                    }
                }
            }
        }
        __syncthreads();
        { // pool 2x2 + relu, accumulate in registers
            #pragma unroll
            for (int i7 = 0; i7 < 7; ++i7) {
                const int pos = pbase + 4 * i7;
                if (pos < 25) {
                    const int pr = pos / 5, pc = pos - pr * 5;
                    const int p0 = pr * 20 + pc * 2;
                    float m = fmaxf(fmaxf(sconv[p0 * 66 + pch], sconv[(p0 + 1) * 66 + pch]),
                                    fmaxf(sconv[(p0 + 10) * 66 + pch], sconv[(p0 + 11) * 66 + pch]));
                    pacc[i7] += fmaxf(m, 0.f);
                }
            }
        }
    }

    const int grp = (blockIdx.x * IPB) >> 9;   // all IPB images share one group
    #pragma unroll
    for (int i7 = 0; i7 < 7; ++i7) {
        const int pos = pbase + 4 * i7;
        if (pos < 25)
            atomicAdd(&gsum[grp * EMB + pos * 64 + pch], pacc[i7]);
    }
}

// mean/512 -> max over 16 groups -> dot with v -> + (fc1b . fc2w) + fc2b -> sigmoid
__global__ __launch_bounds__(256) void head2(
        const float* __restrict__ gsum, const float* __restrict__ v,
        const float* __restrict__ fc1b, const float* __restrict__ fc2w,
        const float* __restrict__ fc2b, float* __restrict__ out)
{
    __shared__ float sred[256];
    const int tid = threadIdx.x;
    float partial = 0.f;
    for (int d = tid; d < EMB; d += 256) {
        float m = gsum[d];
        #pragma unroll
        for (int gg = 1; gg < GROUPS; ++gg) m = fmaxf(m, gsum[gg * EMB + d]);
        partial += (m * (1.f / 512.f)) * v[d];
    }
    partial += fc1b[tid] * fc2w[tid] + fc1b[tid + 256] * fc2w[tid + 256];
    sred[tid] = partial;
    __syncthreads();
    for (int s = 128; s > 0; s >>= 1) {
        if (tid < s) sred[tid] += sred[tid + s];
        __syncthreads();
    }
    if (tid == 0) out[0] = 1.f / (1.f + expf(-(sred[0] + fc2b[0])));
}

extern "C" void kernel_launch(void* const* d_in, const int* in_sizes, int n_in,
                              void* d_out, int out_size, void* d_ws, size_t ws_size,
                              hipStream_t stream)
{
    const float* x    = (const float*)d_in[0];
    const float* w1   = (const float*)d_in[1];
    const float* b1   = (const float*)d_in[2];
    const float* w2   = (const float*)d_in[3];
    const float* b2   = (const float*)d_in[4];
    const float* fc1w = (const float*)d_in[5];
    const float* fc1b = (const float*)d_in[6];
    const float* fc2w = (const float*)d_in[7];
    const float* fc2b = (const float*)d_in[8];

    float* gsum = (float*)d_ws;
    unsigned short* w2f = (unsigned short*)((char*)d_ws + WS_W2F);
    float* v = (float*)((char*)d_ws + WS_V);

    hipMemsetAsync(gsum, 0, GROUPS * EMB * sizeof(float), stream);
    prep_w2<<<72, 256, 0, stream>>>(w2, w2f);
    prep_v<<<(EMB + 63) / 64, 64, 0, stream>>>(fc1w, fc2w, v);
    fused<<<N_IMG / IPB, 256, 0, stream>>>(x, w1, b1, w2f, b2, gsum);
    head2<<<1, 256, 0, stream>>>(gsum, v, fc1b, fc2w, fc2b, (float*)d_out);
}

// Round 3
// 97.612 us; speedup vs baseline: 5.4309x; 1.4459x over previous
//
#include <hip/hip_runtime.h>
#include <math.h>

#define N_IMG 8192
#define GROUPS 16
#define EMB 1600
#define IPB 4

typedef __attribute__((ext_vector_type(8))) short short8;
typedef __attribute__((ext_vector_type(4))) float f32x4;

// ws layout (bytes): gsum[16*1600 f32]@0 ; w2f[18432 bf16]@102400 ;
//                    w1f[1024 bf16]@139264 ; v[1600 f32]@141312
#define WS_W2F 102400
#define WS_W1F 139264
#define WS_V   141312

__device__ __forceinline__ unsigned short f2bf(float f) {
    unsigned u = __builtin_bit_cast(unsigned, f);
    u = (u + 0x7FFFu + ((u >> 16) & 1u)) >> 16;   // RNE
    return (unsigned short)u;
}

// conv2 weights -> frag order: w2f[((s*4+g)*64+n)*8+j], k = ci = 8g+j
__global__ void prep_w2(const float* __restrict__ w2, unsigned short* __restrict__ w2f) {
    int i = blockIdx.x * 256 + threadIdx.x;
    if (i < 18432) {
        int j = i & 7, n = (i >> 3) & 63, g = (i >> 9) & 3, s = i >> 11;
        w2f[i] = f2bf(w2[(s * 32 + 8 * g + j) * 64 + n]);
    }
}

// conv1 weights -> frag order with custom k-map kappa and col map co=2*l15+jn.
// kappa: g0: j(0..5) -> e=(j>>1)*3+(j&1) ; j6->e2 ; j7->e5 ; g1: j0->e8 ; else 0
__global__ void prep_w1(const float* __restrict__ w1, unsigned short* __restrict__ w1f) {
    int i = blockIdx.x * 256 + threadIdx.x;   // 1024 entries
    if (i < 1024) {
        int j = i & 7, jn = (i >> 3) & 1, l15 = (i >> 4) & 15, g = i >> 8;
        int e = -1;
        if (g == 0) e = (j < 6) ? ((j >> 1) * 3 + (j & 1)) : (j == 6 ? 2 : 5);
        else if (g == 1 && j == 0) e = 8;
        int co = 2 * l15 + jn;
        w1f[i] = (e >= 0) ? f2bf(w1[e * 32 + co]) : (unsigned short)0;
    }
}

// v[d] = sum_j fc1w[d][j] * fc2w[j]
__global__ void prep_v(const float* __restrict__ fc1w, const float* __restrict__ fc2w,
                       float* __restrict__ v) {
    int d = blockIdx.x * 64 + threadIdx.x;
    if (d >= EMB) return;
    const float4* a = (const float4*)(fc1w + d * 512);
    const float4* b = (const float4*)fc2w;
    float s = 0.f;
    for (int q = 0; q < 128; ++q) {
        float4 av = a[q], bv = b[q];
        s += av.x * bv.x + av.y * bv.y + av.z * bv.z + av.w * bv.w;
    }
    v[d] = s;
}

// ---------------------------------------------------------------------------
// Both convs via MFMA, quad-mapped M (2x2 pool quad lives in one lane's 4
// accum regs -> in-lane pool+relu). No f32 conv buffer, no pool stage.
// ---------------------------------------------------------------------------
__global__ __launch_bounds__(256) void fused(
        const float* __restrict__ x,
        const unsigned short* __restrict__ w1f, const float* __restrict__ b1v,
        const unsigned short* __restrict__ w2f, const float* __restrict__ b2,
        float* __restrict__ gsum)
{
    __shared__ __align__(16) unsigned short simg[784];      // bf16 image
    __shared__ __align__(16) unsigned short sp2[144 * 40];  // [pos12x12][40ch]

    const int tid = threadIdx.x;
    const int w = tid >> 6, mw = w & 1, nw = w >> 1;
    const int g = (tid >> 4) & 3, l15 = tid & 15;

    // conv1 B-frags (8 VGPR)
    short8 wb1[2];
    wb1[0] = *(const short8*)(w1f + ((g * 16 + l15) * 2 + 0) * 8);
    wb1[1] = *(const short8*)(w1f + ((g * 16 + l15) * 2 + 1) * 8);
    const float c1b0 = b1v[2 * l15], c1b1 = b1v[2 * l15 + 1];

    // conv2 B-frags (72 VGPR)
    short8 bb[9][2];
    #pragma unroll
    for (int s = 0; s < 9; ++s)
        #pragma unroll
        for (int j = 0; j < 2; ++j)
            bb[s][j] = *(const short8*)(w2f + ((s * 4 + g) * 64 + 32 * nw + 16 * j + l15) * 8);
    const float c2b0 = b2[32 * nw + l15], c2b1 = b2[32 * nw + 16 + l15];

    float pacc[4][2];
    #pragma unroll
    for (int i = 0; i < 4; ++i) { pacc[i][0] = 0.f; pacc[i][1] = 0.f; }

    for (int ii = 0; ii < IPB; ++ii) {
        const int img = blockIdx.x * IPB + ii;
        __syncthreads();
        if (tid < 196) {   // image -> LDS as bf16
            float4 p = ((const float4*)(x + img * 784))[tid];
            uint2 pk;
            pk.x = (unsigned)f2bf(p.x) | ((unsigned)f2bf(p.y) << 16);
            pk.y = (unsigned)f2bf(p.z) | ((unsigned)f2bf(p.w) << 16);
            *(uint2*)(&simg[4 * tid]) = pk;
        }
        __syncthreads();

        // ---- conv1 MFMA: 36 M-tiles over 4 waves, K=9 padded into K=32 ----
        for (int i9 = 0; i9 < 9; ++i9) {
            const int t1 = w + 4 * i9;            // 0..35
            const int m = 16 * t1 + l15;
            const int q = m >> 2, idx = m & 3;
            const int qr = q / 12, qc = q - 12 * qr;
            const int r = 2 * qr + (idx >> 1), c = 2 * qc + (idx & 1);
            const int base = r * 28 + c;
            short8 af = {0, 0, 0, 0, 0, 0, 0, 0};
            if (g == 0) {
                af[0] = simg[base];      af[1] = simg[base + 1];
                af[2] = simg[base + 28]; af[3] = simg[base + 29];
                af[4] = simg[base + 56]; af[5] = simg[base + 57];
                af[6] = simg[base + 2];  af[7] = simg[base + 30];
            } else if (g == 1) {
                af[0] = simg[base + 58];
            }
            f32x4 a0 = {c1b0, c1b0, c1b0, c1b0};
            f32x4 a1 = {c1b1, c1b1, c1b1, c1b1};
            a0 = __builtin_amdgcn_mfma_f32_16x16x32_bf16(af, wb1[0], a0, 0, 0, 0);
            a1 = __builtin_amdgcn_mfma_f32_16x16x32_bf16(af, wb1[1], a1, 0, 0, 0);
            // in-lane pool+relu, write pooled pair (ch 2*l15, 2*l15+1)
            float p0 = fmaxf(fmaxf(fmaxf(a0[0], a0[1]), fmaxf(a0[2], a0[3])), 0.f);
            float p1 = fmaxf(fmaxf(fmaxf(a1[0], a1[1]), fmaxf(a1[2], a1[3])), 0.f);
            const int qd = 4 * t1 + g;            // this lane's output quad
            *(unsigned*)(&sp2[qd * 40 + 2 * l15]) =
                (unsigned)f2bf(p0) | ((unsigned)f2bf(p1) << 16);
        }
        __syncthreads();

        // ---- conv2 MFMA: quad-mapped M=100, K=288, accumulate pooled ----
        #pragma unroll 4
        for (int ti = 0; ti < 4; ++ti) {
            const int t2 = mw + 2 * ti;
            if (t2 < 7) {
                int m2 = 16 * t2 + l15; if (m2 > 99) m2 = 99;
                const int q2 = m2 >> 2, idx = m2 & 3;
                const int qr = q2 / 5, qc = q2 - 5 * qr;
                const int r2 = 2 * qr + (idx >> 1), c2 = 2 * qc + (idx & 1);
                const unsigned short* ab = sp2 + (r2 * 12 + c2) * 40 + 8 * g;
                f32x4 a0 = {c2b0, c2b0, c2b0, c2b0};
                f32x4 a1 = {c2b1, c2b1, c2b1, c2b1};
                #pragma unroll
                for (int s = 0; s < 9; ++s) {
                    short8 af2 = *(const short8*)(ab + ((s / 3) * 12 + (s % 3)) * 40);
                    a0 = __builtin_amdgcn_mfma_f32_16x16x32_bf16(af2, bb[s][0], a0, 0, 0, 0);
                    a1 = __builtin_amdgcn_mfma_f32_16x16x32_bf16(af2, bb[s][1], a1, 0, 0, 0);
                }
                pacc[ti][0] += fmaxf(fmaxf(fmaxf(a0[0], a0[1]), fmaxf(a0[2], a0[3])), 0.f);
                pacc[ti][1] += fmaxf(fmaxf(fmaxf(a1[0], a1[1]), fmaxf(a1[2], a1[3])), 0.f);
            }
        }
    }

    // one atomic per (quad, channel) per block
    const int grp = (blockIdx.x * IPB) >> 9;
    #pragma unroll 4
    for (int ti = 0; ti < 4; ++ti) {
        const int t2 = mw + 2 * ti;
        const int q2 = 4 * t2 + g;
        if (t2 < 7 && q2 <= 24) {
            atomicAdd(&gsum[grp * EMB + q2 * 64 + 32 * nw + l15],      pacc[ti][0]);
            atomicAdd(&gsum[grp * EMB + q2 * 64 + 32 * nw + 16 + l15], pacc[ti][1]);
        }
    }
}

// mean/512 -> max over 16 groups -> dot v -> + fc1b.fc2w + fc2b -> sigmoid
__global__ __launch_bounds__(256) void head2(
        const float* __restrict__ gsum, const float* __restrict__ v,
        const float* __restrict__ fc1b, const float* __restrict__ fc2w,
        const float* __restrict__ fc2b, float* __restrict__ out)
{
    __shared__ float sred[256];
    const int tid = threadIdx.x;
    float partial = 0.f;
    for (int d = tid; d < EMB; d += 256) {
        float m = gsum[d];
        #pragma unroll
        for (int gg = 1; gg < GROUPS; ++gg) m = fmaxf(m, gsum[gg * EMB + d]);
        partial += (m * (1.f / 512.f)) * v[d];
    }
    partial += fc1b[tid] * fc2w[tid] + fc1b[tid + 256] * fc2w[tid + 256];
    sred[tid] = partial;
    __syncthreads();
    for (int s = 128; s > 0; s >>= 1) {
        if (tid < s) sred[tid] += sred[tid + s];
        __syncthreads();
    }
    if (tid == 0) out[0] = 1.f / (1.f + expf(-(sred[0] + fc2b[0])));
}

extern "C" void kernel_launch(void* const* d_in, const int* in_sizes, int n_in,
                              void* d_out, int out_size, void* d_ws, size_t ws_size,
                              hipStream_t stream)
{
    const float* x    = (const float*)d_in[0];
    const float* w1   = (const float*)d_in[1];
    const float* b1   = (const float*)d_in[2];
    const float* w2   = (const float*)d_in[3];
    const float* b2   = (const float*)d_in[4];
    const float* fc1w = (const float*)d_in[5];
    const float* fc1b = (const float*)d_in[6];
    const float* fc2w = (const float*)d_in[7];
    const float* fc2b = (const float*)d_in[8];

    float* gsum = (float*)d_ws;
    unsigned short* w2f = (unsigned short*)((char*)d_ws + WS_W2F);
    unsigned short* w1f = (unsigned short*)((char*)d_ws + WS_W1F);
    float* v = (float*)((char*)d_ws + WS_V);

    hipMemsetAsync(gsum, 0, GROUPS * EMB * sizeof(float), stream);
    prep_w2<<<72, 256, 0, stream>>>(w2, w2f);
    prep_w1<<<4, 256, 0, stream>>>(w1, w1f);
    prep_v<<<(EMB + 63) / 64, 64, 0, stream>>>(fc1w, fc2w, v);
    fused<<<N_IMG / IPB, 256, 0, stream>>>(x, w1f, b1, w2f, b2, gsum);
    head2<<<1, 256, 0, stream>>>(gsum, v, fc1b, fc2w, fc2b, (float*)d_out);
}